// Round 1
// baseline (19021.404 us; speedup 1.0000x reference)
//
#include <hip/hip_runtime.h>

static constexpr int NN = 100000;   // nodes
static constexpr int NE = 3200000;  // edges
static constexpr float EPS = 1e-5f;

// ---- degree / dinv -------------------------------------------------------
__global__ void k_deg(const int* __restrict__ dst, float* __restrict__ deg) {
    int e = blockIdx.x * blockDim.x + threadIdx.x;
    if (e < NE) unsafeAtomicAdd(&deg[dst[e]], 1.0f);
}

__global__ void k_dinv(float* __restrict__ deg) {
    int i = blockIdx.x * blockDim.x + threadIdx.x;
    if (i < NN) deg[i] = rsqrtf(deg[i] + 1.0f);
}

// ---- hs = dinv[i] * (in[i,:] @ W) ---------------------------------------
template<int IN, int OUT>
__global__ void k_linear_scale(const float* __restrict__ in, const float* __restrict__ W,
                               const float* __restrict__ dinv, float* __restrict__ hs) {
    int idx = blockIdx.x * blockDim.x + threadIdx.x;
    if (idx >= NN * OUT) return;
    int i = idx / OUT, f = idx - i * OUT;
    float a = 0.f;
    #pragma unroll
    for (int k = 0; k < IN; ++k) a += in[i * IN + k] * W[k * OUT + f];
    hs[idx] = a * dinv[i];
}

// ---- acc[dst] += hs[src]  (per-edge thread, float4 gather + 4 atomics) ---
template<int OUT>
__global__ void k_scatter(const int* __restrict__ src, const int* __restrict__ dst,
                          const float* __restrict__ hs, float* __restrict__ acc) {
    int e = blockIdx.x * blockDim.x + threadIdx.x;
    if (e >= NE) return;
    int s = src[e], d = dst[e];
    const float* hp = hs + (size_t)s * OUT;
    float* ap = acc + (size_t)d * OUT;
    if constexpr (OUT % 4 == 0) {
        #pragma unroll
        for (int c = 0; c < OUT / 4; ++c) {
            float4 v = reinterpret_cast<const float4*>(hp)[c];
            unsafeAtomicAdd(ap + 4 * c + 0, v.x);
            unsafeAtomicAdd(ap + 4 * c + 1, v.y);
            unsafeAtomicAdd(ap + 4 * c + 2, v.z);
            unsafeAtomicAdd(ap + 4 * c + 3, v.w);
        }
    } else {
        #pragma unroll
        for (int c = 0; c < OUT; ++c) unsafeAtomicAdd(ap + c, hp[c]);
    }
}

// ---- out = post( dinv*(acc+hs) + b );  MODE: 0 none, 1 relu, 2 bn+relu ---
template<int OUT, int MODE>
__global__ void k_finalize(const float* __restrict__ hs, const float* __restrict__ acc,
                           const float* __restrict__ dinv, const float* __restrict__ b,
                           const float* __restrict__ g, const float* __restrict__ be,
                           const float* __restrict__ m, const float* __restrict__ v,
                           float* __restrict__ out) {
    int idx = blockIdx.x * blockDim.x + threadIdx.x;
    if (idx >= NN * OUT) return;
    int i = idx / OUT, f = idx - i * OUT;
    float z = dinv[i] * (acc[idx] + hs[idx]) + b[f];
    if constexpr (MODE == 2) z = (z - m[f]) * rsqrtf(v[f] + EPS) * g[f] + be[f];
    if constexpr (MODE >= 1) z = fmaxf(z, 0.f);
    out[idx] = z;
}

extern "C" void kernel_launch(void* const* d_in, const int* in_sizes, int n_in,
                              void* d_out, int out_size, void* d_ws, size_t ws_size,
                              hipStream_t stream) {
    const float* x   = (const float*)d_in[0];
    const int*   src = (const int*)  d_in[1];
    const int*   dst = (const int*)  d_in[2];
    const float* W1  = (const float*)d_in[3];
    const float* b1  = (const float*)d_in[4];
    const float* g1  = (const float*)d_in[5];
    const float* be1 = (const float*)d_in[6];
    const float* m1  = (const float*)d_in[7];
    const float* v1  = (const float*)d_in[8];
    const float* W2  = (const float*)d_in[9];
    const float* b2  = (const float*)d_in[10];
    const float* g2  = (const float*)d_in[11];
    const float* be2 = (const float*)d_in[12];
    const float* m2  = (const float*)d_in[13];
    const float* v2  = (const float*)d_in[14];
    const float* W3  = (const float*)d_in[15];
    const float* b3  = (const float*)d_in[16];
    const float* W4  = (const float*)d_in[17];
    const float* b4  = (const float*)d_in[18];
    float* out = (float*)d_out;

    float* ws   = (float*)d_ws;
    float* dinv = ws;                       // NN floats
    float* X    = ws + 100352;              // NN*64 (input/output rotating)
    float* HS   = X + (size_t)NN * 64;      // NN*64
    float* ACC  = HS + (size_t)NN * 64;     // NN*64

    const int BLK = 256;
    const int gE  = (NE + BLK - 1) / BLK;
    const int gN  = (NN + BLK - 1) / BLK;
    auto gNF = [&](int f) { return (NN * f + BLK - 1) / BLK; };

    // degree -> dinv (in place)
    hipMemsetAsync(dinv, 0, NN * sizeof(float), stream);
    k_deg<<<gE, BLK, 0, stream>>>(dst, dinv);
    k_dinv<<<gN, BLK, 0, stream>>>(dinv);

    // ---- Layer 1: 5 -> 64, BN + ReLU ----
    k_linear_scale<5, 64><<<gNF(64), BLK, 0, stream>>>(x, W1, dinv, HS);
    hipMemsetAsync(ACC, 0, (size_t)NN * 64 * sizeof(float), stream);
    k_scatter<64><<<gE, BLK, 0, stream>>>(src, dst, HS, ACC);
    k_finalize<64, 2><<<gNF(64), BLK, 0, stream>>>(HS, ACC, dinv, b1, g1, be1, m1, v1, X);

    // ---- Layer 2: 64 -> 32, BN + ReLU ----
    k_linear_scale<64, 32><<<gNF(32), BLK, 0, stream>>>(X, W2, dinv, HS);
    hipMemsetAsync(ACC, 0, (size_t)NN * 32 * sizeof(float), stream);
    k_scatter<32><<<gE, BLK, 0, stream>>>(src, dst, HS, ACC);
    k_finalize<32, 2><<<gNF(32), BLK, 0, stream>>>(HS, ACC, dinv, b2, g2, be2, m2, v2, X);

    // ---- Layer 3: 32 -> 16, ReLU ----
    k_linear_scale<32, 16><<<gNF(16), BLK, 0, stream>>>(X, W3, dinv, HS);
    hipMemsetAsync(ACC, 0, (size_t)NN * 16 * sizeof(float), stream);
    k_scatter<16><<<gE, BLK, 0, stream>>>(src, dst, HS, ACC);
    k_finalize<16, 1><<<gNF(16), BLK, 0, stream>>>(HS, ACC, dinv, b3, nullptr, nullptr, nullptr, nullptr, X);

    // ---- Layer 4: 16 -> 3 (logits) ----
    k_linear_scale<16, 3><<<gNF(3), BLK, 0, stream>>>(X, W4, dinv, HS);
    hipMemsetAsync(ACC, 0, (size_t)NN * 3 * sizeof(float), stream);
    k_scatter<3><<<gE, BLK, 0, stream>>>(src, dst, HS, ACC);
    k_finalize<3, 0><<<gNF(3), BLK, 0, stream>>>(HS, ACC, dinv, b4, nullptr, nullptr, nullptr, nullptr, out);
}

// Round 2
// 962.113 us; speedup vs baseline: 19.7704x; 19.7704x over previous
//
#include <hip/hip_runtime.h>

static constexpr int NN = 100000;   // nodes
static constexpr int NE = 3200000;  // edges
static constexpr float EPS = 1e-5f;
static constexpr int SCAN_B = 256;
static constexpr int NBLK = (NN + SCAN_B - 1) / SCAN_B;   // 391

// ---- histogram of dst ----------------------------------------------------
__global__ void k_hist(const int* __restrict__ dst, int* __restrict__ cnt) {
    int e = blockIdx.x * blockDim.x + threadIdx.x;
    if (e < NE) atomicAdd(&cnt[dst[e]], 1);
}

__global__ void k_dinv(const int* __restrict__ cnt, float* __restrict__ dinv) {
    int i = blockIdx.x * blockDim.x + threadIdx.x;
    if (i < NN) dinv[i] = rsqrtf((float)cnt[i] + 1.0f);
}

// ---- 3-kernel exclusive scan over cnt -> excl (becomes row_ptr) ----------
__global__ void k_scan1(const int* __restrict__ cnt, int* __restrict__ excl,
                        int* __restrict__ bsum) {
    __shared__ int s[SCAN_B];
    int gid = blockIdx.x * SCAN_B + threadIdx.x;
    int v = (gid < NN) ? cnt[gid] : 0;
    s[threadIdx.x] = v;
    __syncthreads();
    for (int off = 1; off < SCAN_B; off <<= 1) {
        int t = (threadIdx.x >= off) ? s[threadIdx.x - off] : 0;
        __syncthreads();
        s[threadIdx.x] += t;
        __syncthreads();
    }
    if (gid < NN) excl[gid] = s[threadIdx.x] - v;          // exclusive
    if (threadIdx.x == SCAN_B - 1) bsum[blockIdx.x] = s[threadIdx.x];
}

__global__ void k_scan2(int* __restrict__ bsum) {
    __shared__ int s[512];
    int tid = threadIdx.x;
    int v = (tid < NBLK) ? bsum[tid] : 0;
    s[tid] = v;
    __syncthreads();
    for (int off = 1; off < 512; off <<= 1) {
        int t = (tid >= off) ? s[tid - off] : 0;
        __syncthreads();
        s[tid] += t;
        __syncthreads();
    }
    if (tid < NBLK) bsum[tid] = s[tid] - v;                // exclusive
}

__global__ void k_scan3(int* __restrict__ excl, const int* __restrict__ bsum) {
    int i = blockIdx.x * blockDim.x + threadIdx.x;
    if (i < NN) excl[i] += bsum[i / SCAN_B];
}

// ---- fill CSR: csr[row_ptr[d] + pos] = src -------------------------------
__global__ void k_fill(const int* __restrict__ src, const int* __restrict__ dst,
                       const int* __restrict__ row_ptr, int* __restrict__ cursor,
                       int* __restrict__ csr) {
    int e = blockIdx.x * blockDim.x + threadIdx.x;
    if (e >= NE) return;
    int d = dst[e];
    int pos = atomicAdd(&cursor[d], 1);
    csr[row_ptr[d] + pos] = src[e];
}

// ---- hs = dinv[i] * (in[i,:] @ W) ---------------------------------------
template<int IN, int OUT>
__global__ void k_linear_scale(const float* __restrict__ in, const float* __restrict__ W,
                               const float* __restrict__ dinv, float* __restrict__ hs) {
    int idx = blockIdx.x * blockDim.x + threadIdx.x;
    if (idx >= NN * OUT) return;
    int i = idx / OUT, f = idx - i * OUT;
    float a = 0.f;
    #pragma unroll
    for (int k = 0; k < IN; ++k) a += in[i * IN + k] * W[k * OUT + f];
    hs[idx] = a * dinv[i];
}

// ---- wave-per-node gather + fused finalize -------------------------------
// MODE: 0 none, 1 relu, 2 bn+relu
template<int F, int MODE>
__global__ void k_gather(const int* __restrict__ row_ptr, const int* __restrict__ cnt,
                         const int* __restrict__ csr, const float* __restrict__ hs,
                         const float* __restrict__ dinv, const float* __restrict__ b,
                         const float* __restrict__ g, const float* __restrict__ be,
                         const float* __restrict__ m, const float* __restrict__ vv,
                         float* __restrict__ out) {
    constexpr int Fpad = (F == 3) ? 4 : F;
    constexpr int LOG  = (Fpad == 64) ? 6 : (Fpad == 32) ? 5 : (Fpad == 16) ? 4 : 2;
    constexpr int SUBS = 64 / Fpad;

    int node = (blockIdx.x * blockDim.x + threadIdx.x) >> 6;   // wave id
    if (node >= NN) return;
    int lane = threadIdx.x & 63;
    int f   = lane & (Fpad - 1);
    int sub = lane >> LOG;

    int start = row_ptr[node];
    int n     = cnt[node];

    float a = 0.f;
    for (int j = sub; j < n; j += SUBS) {
        int s = csr[start + j];
        if (f < F) a += hs[(size_t)s * F + f];
    }
    #pragma unroll
    for (int mask = Fpad; mask < 64; mask <<= 1) a += __shfl_xor(a, mask);

    if (lane < F) {
        float self = hs[(size_t)node * F + f];
        float z = dinv[node] * (a + self) + b[f];
        if constexpr (MODE == 2) z = (z - m[f]) * rsqrtf(vv[f] + EPS) * g[f] + be[f];
        if constexpr (MODE >= 1) z = fmaxf(z, 0.f);
        out[(size_t)node * F + f] = z;
    }
}

extern "C" void kernel_launch(void* const* d_in, const int* in_sizes, int n_in,
                              void* d_out, int out_size, void* d_ws, size_t ws_size,
                              hipStream_t stream) {
    const float* x   = (const float*)d_in[0];
    const int*   src = (const int*)  d_in[1];
    const int*   dst = (const int*)  d_in[2];
    const float* W1  = (const float*)d_in[3];
    const float* b1  = (const float*)d_in[4];
    const float* g1  = (const float*)d_in[5];
    const float* be1 = (const float*)d_in[6];
    const float* m1  = (const float*)d_in[7];
    const float* v1  = (const float*)d_in[8];
    const float* W2  = (const float*)d_in[9];
    const float* b2  = (const float*)d_in[10];
    const float* g2  = (const float*)d_in[11];
    const float* be2 = (const float*)d_in[12];
    const float* m2  = (const float*)d_in[13];
    const float* v2  = (const float*)d_in[14];
    const float* W3  = (const float*)d_in[15];
    const float* b3  = (const float*)d_in[16];
    const float* W4  = (const float*)d_in[17];
    const float* b4  = (const float*)d_in[18];
    float* out = (float*)d_out;

    // workspace layout (4-byte elements)
    char* wsb = (char*)d_ws;
    float* dinv   = (float*)wsb;                  // 100352
    int*   cnt    = (int*)(wsb + 100352ull * 4);  // 100352
    int*   rowp   = (int*)(wsb + 200704ull * 4);  // 100352 (excl scan, becomes row_ptr)
    int*   bsum   = (int*)(wsb + 301056ull * 4);  // 512
    int*   cursor = (int*)(wsb + 301568ull * 4);  // 100352
    int*   csr    = (int*)(wsb + 401920ull * 4);  // NE
    float* X      = (float*)(wsb + (401920ull + NE) * 4);            // NN*64
    float* HS     = (float*)(wsb + (401920ull + NE + 6400000ull) * 4); // NN*64

    const int BLK = 256;
    const int gE  = (NE + BLK - 1) / BLK;
    const int gN  = (NN + BLK - 1) / BLK;
    const int gW  = (NN * 64 + BLK - 1) / BLK;    // wave-per-node grids
    auto gNF = [&](int f) { return (NN * f + BLK - 1) / BLK; };

    // ---- CSR build + dinv ----
    hipMemsetAsync(cnt, 0, NN * sizeof(int), stream);
    hipMemsetAsync(cursor, 0, NN * sizeof(int), stream);
    k_hist <<<gE, BLK, 0, stream>>>(dst, cnt);
    k_dinv <<<gN, BLK, 0, stream>>>(cnt, dinv);
    k_scan1<<<NBLK, SCAN_B, 0, stream>>>(cnt, rowp, bsum);
    k_scan2<<<1, 512, 0, stream>>>(bsum);
    k_scan3<<<gN, BLK, 0, stream>>>(rowp, bsum);
    k_fill <<<gE, BLK, 0, stream>>>(src, dst, rowp, cursor, csr);

    // ---- Layer 1: 5 -> 64, BN + ReLU ----
    k_linear_scale<5, 64><<<gNF(64), BLK, 0, stream>>>(x, W1, dinv, HS);
    k_gather<64, 2><<<gW, BLK, 0, stream>>>(rowp, cnt, csr, HS, dinv, b1, g1, be1, m1, v1, X);

    // ---- Layer 2: 64 -> 32, BN + ReLU ----
    k_linear_scale<64, 32><<<gNF(32), BLK, 0, stream>>>(X, W2, dinv, HS);
    k_gather<32, 2><<<gW, BLK, 0, stream>>>(rowp, cnt, csr, HS, dinv, b2, g2, be2, m2, v2, X);

    // ---- Layer 3: 32 -> 16, ReLU ----
    k_linear_scale<32, 16><<<gNF(16), BLK, 0, stream>>>(X, W3, dinv, HS);
    k_gather<16, 1><<<gW, BLK, 0, stream>>>(rowp, cnt, csr, HS, dinv, b3, nullptr, nullptr, nullptr, nullptr, X);

    // ---- Layer 4: 16 -> 3 (logits) ----
    k_linear_scale<16, 3><<<gNF(3), BLK, 0, stream>>>(X, W4, dinv, HS);
    k_gather<3, 0><<<gW, BLK, 0, stream>>>(rowp, cnt, csr, HS, dinv, b4, nullptr, nullptr, nullptr, nullptr, out);
}

// Round 3
// 675.628 us; speedup vs baseline: 28.1537x; 1.4240x over previous
//
#include <hip/hip_runtime.h>

static constexpr int NN = 100000;   // nodes
static constexpr int NE = 3200000;  // edges
static constexpr float EPS = 1e-5f;
static constexpr int SCAN_B = 256;
static constexpr int NBLK = (NN + SCAN_B - 1) / SCAN_B;   // 391

// ---- histogram of dst ----------------------------------------------------
__global__ void k_hist(const int* __restrict__ dst, int* __restrict__ cnt) {
    int e = blockIdx.x * blockDim.x + threadIdx.x;
    if (e < NE) atomicAdd(&cnt[dst[e]], 1);
}

__global__ void k_dinv(const int* __restrict__ cnt, float* __restrict__ dinv) {
    int i = blockIdx.x * blockDim.x + threadIdx.x;
    if (i < NN) dinv[i] = rsqrtf((float)cnt[i] + 1.0f);
}

// ---- exclusive scan over cnt -> rowp -------------------------------------
__global__ void k_scan1(const int* __restrict__ cnt, int* __restrict__ excl,
                        int* __restrict__ bsum) {
    __shared__ int s[SCAN_B];
    int gid = blockIdx.x * SCAN_B + threadIdx.x;
    int v = (gid < NN) ? cnt[gid] : 0;
    s[threadIdx.x] = v;
    __syncthreads();
    for (int off = 1; off < SCAN_B; off <<= 1) {
        int t = (threadIdx.x >= off) ? s[threadIdx.x - off] : 0;
        __syncthreads();
        s[threadIdx.x] += t;
        __syncthreads();
    }
    if (gid < NN) excl[gid] = s[threadIdx.x] - v;
    if (threadIdx.x == SCAN_B - 1) bsum[blockIdx.x] = s[threadIdx.x];
}

__global__ void k_scan2(int* __restrict__ bsum) {
    __shared__ int s[512];
    int tid = threadIdx.x;
    int v = (tid < NBLK) ? bsum[tid] : 0;
    s[tid] = v;
    __syncthreads();
    for (int off = 1; off < 512; off <<= 1) {
        int t = (tid >= off) ? s[tid - off] : 0;
        __syncthreads();
        s[tid] += t;
        __syncthreads();
    }
    if (tid < NBLK) bsum[tid] = s[tid] - v;
}

__global__ void k_scan3(int* __restrict__ excl, const int* __restrict__ bsum,
                        int* __restrict__ cursor) {
    int i = blockIdx.x * blockDim.x + threadIdx.x;
    if (i < NN) {
        int r = excl[i] + bsum[i / SCAN_B];
        excl[i] = r;
        cursor[i] = r;     // seed fill cursor with row_ptr
    }
}

// ---- fill CSR: csr[cursor[d]++] = src ------------------------------------
__global__ void k_fill(const int* __restrict__ src, const int* __restrict__ dst,
                       int* __restrict__ cursor, int* __restrict__ csr) {
    int e = blockIdx.x * blockDim.x + threadIdx.x;
    if (e >= NE) return;
    int pos = atomicAdd(&cursor[dst[e]], 1);
    csr[pos] = src[e];
}

// ---- layer-1 staging: q[i, 0..7] = dinv[i]*x[i, 0..4], pad 0 -------------
__global__ void k_stage1(const float* __restrict__ x, const float* __restrict__ dinv,
                         float* __restrict__ q) {
    int idx = blockIdx.x * blockDim.x + threadIdx.x;
    if (idx >= NN * 8) return;
    int i = idx >> 3, k = idx & 7;
    q[idx] = (k < 5) ? x[i * 5 + k] * dinv[i] : 0.f;
}

// ---- hs = dinv[i] * (in[i,:] @ W), OUTP-padded rows ----------------------
template<int IN, int OUT, int OUTP>
__global__ void k_linear_scale(const float* __restrict__ in, const float* __restrict__ W,
                               const float* __restrict__ dinv, float* __restrict__ hs) {
    int idx = blockIdx.x * blockDim.x + threadIdx.x;
    if (idx >= NN * OUTP) return;
    int i = idx / OUTP, f = idx - i * OUTP;
    float a = 0.f;
    if (f < OUT) {
        #pragma unroll
        for (int k = 0; k < IN; ++k) a += in[i * IN + k] * W[k * OUT + f];
        a *= dinv[i];
    }
    hs[idx] = a;
}

// ---- wave-per-node float4 gather + fused finalize -------------------------
// F = padded feature width (multiple of 4). MODE: 0 scale only (write F),
// 1 bias+relu, 2 bias+bn+relu, 3 bias only + write 3 floats (logits).
template<int F, int MODE>
__global__ void k_gather(const int* __restrict__ row_ptr, const int* __restrict__ cnt,
                         const int* __restrict__ csr, const float* __restrict__ hs,
                         const float* __restrict__ dinv, const float* __restrict__ b,
                         const float* __restrict__ g, const float* __restrict__ be,
                         const float* __restrict__ m, const float* __restrict__ vv,
                         float* __restrict__ out) {
    constexpr int F4  = F / 4;        // lanes per edge
    constexpr int EPI = 64 / F4;      // edges per iteration

    int node = (blockIdx.x * blockDim.x + threadIdx.x) >> 6;
    if (node >= NN) return;
    int lane = threadIdx.x & 63;
    int c = lane & (F4 - 1);          // float4 column within row
    int e = lane / F4;                // edge slot

    int start = row_ptr[node];
    int n     = cnt[node];

    float4 a = make_float4(0.f, 0.f, 0.f, 0.f);
    for (int j = e; j < n; j += EPI) {
        int s = csr[start + j];
        float4 v = reinterpret_cast<const float4*>(hs + (size_t)s * F)[c];
        a.x += v.x; a.y += v.y; a.z += v.z; a.w += v.w;
    }
    #pragma unroll
    for (int mask = F4; mask < 64; mask <<= 1) {
        a.x += __shfl_xor(a.x, mask);
        a.y += __shfl_xor(a.y, mask);
        a.z += __shfl_xor(a.z, mask);
        a.w += __shfl_xor(a.w, mask);
    }

    if (lane < F4) {
        float4 self = reinterpret_cast<const float4*>(hs + (size_t)node * F)[lane];
        float di = dinv[node];
        float4 z;
        z.x = di * (a.x + self.x);
        z.y = di * (a.y + self.y);
        z.z = di * (a.z + self.z);
        z.w = di * (a.w + self.w);
        if constexpr (MODE >= 1) {
            int f0 = lane * 4;
            z.x += b[f0 + 0]; z.y += b[f0 + 1];
            z.z += b[f0 + 2]; z.w += (MODE == 3 ? 0.f : b[f0 + 3]);
            if constexpr (MODE == 2) {
                z.x = (z.x - m[f0+0]) * rsqrtf(vv[f0+0] + EPS) * g[f0+0] + be[f0+0];
                z.y = (z.y - m[f0+1]) * rsqrtf(vv[f0+1] + EPS) * g[f0+1] + be[f0+1];
                z.z = (z.z - m[f0+2]) * rsqrtf(vv[f0+2] + EPS) * g[f0+2] + be[f0+2];
                z.w = (z.w - m[f0+3]) * rsqrtf(vv[f0+3] + EPS) * g[f0+3] + be[f0+3];
            }
            if constexpr (MODE == 1 || MODE == 2) {
                z.x = fmaxf(z.x, 0.f); z.y = fmaxf(z.y, 0.f);
                z.z = fmaxf(z.z, 0.f); z.w = fmaxf(z.w, 0.f);
            }
        }
        if constexpr (MODE == 3) {
            float* o = out + (size_t)node * 3;
            o[0] = z.x; o[1] = z.y; o[2] = z.z;
        } else {
            reinterpret_cast<float4*>(out + (size_t)node * F)[lane] = z;
        }
    }
}

// ---- layer-1 tail: X1 = relu(bn(G[:, :5] @ W1 + b1)) ----------------------
__global__ void k_lin1(const float* __restrict__ G, const float* __restrict__ W1,
                       const float* __restrict__ b1, const float* __restrict__ g1,
                       const float* __restrict__ be1, const float* __restrict__ m1,
                       const float* __restrict__ v1, float* __restrict__ X) {
    int idx = blockIdx.x * blockDim.x + threadIdx.x;
    if (idx >= NN * 64) return;
    int i = idx >> 6, f = idx & 63;
    const float* gr = G + (size_t)i * 8;
    float z = b1[f];
    #pragma unroll
    for (int k = 0; k < 5; ++k) z += gr[k] * W1[k * 64 + f];
    z = (z - m1[f]) * rsqrtf(v1[f] + EPS) * g1[f] + be1[f];
    X[idx] = fmaxf(z, 0.f);
}

extern "C" void kernel_launch(void* const* d_in, const int* in_sizes, int n_in,
                              void* d_out, int out_size, void* d_ws, size_t ws_size,
                              hipStream_t stream) {
    const float* x   = (const float*)d_in[0];
    const int*   src = (const int*)  d_in[1];
    const int*   dst = (const int*)  d_in[2];
    const float* W1  = (const float*)d_in[3];
    const float* b1  = (const float*)d_in[4];
    const float* g1  = (const float*)d_in[5];
    const float* be1 = (const float*)d_in[6];
    const float* m1  = (const float*)d_in[7];
    const float* v1  = (const float*)d_in[8];
    const float* W2  = (const float*)d_in[9];
    const float* b2  = (const float*)d_in[10];
    const float* g2  = (const float*)d_in[11];
    const float* be2 = (const float*)d_in[12];
    const float* m2  = (const float*)d_in[13];
    const float* v2  = (const float*)d_in[14];
    const float* W3  = (const float*)d_in[15];
    const float* b3  = (const float*)d_in[16];
    const float* W4  = (const float*)d_in[17];
    const float* b4  = (const float*)d_in[18];
    float* out = (float*)d_out;

    // workspace layout (4-byte units)
    char* wsb = (char*)d_ws;
    float* dinv   = (float*)wsb;                    // 100352
    int*   cnt    = (int*)(wsb + 100352ull * 4);
    int*   rowp   = (int*)(wsb + 200704ull * 4);
    int*   bsum   = (int*)(wsb + 301056ull * 4);    // 512
    int*   cursor = (int*)(wsb + 301568ull * 4);
    int*   csr    = (int*)(wsb + 401920ull * 4);    // NE
    float* HS     = (float*)(wsb + (401920ull + NE) * 4);             // NN*64
    float* X      = (float*)(wsb + (401920ull + NE + 6400000ull) * 4); // NN*64
    float* G      = (float*)(wsb + (401920ull + NE + 12800000ull) * 4); // NN*8

    const int BLK = 256;
    const int gE  = (NE + BLK - 1) / BLK;
    const int gN  = (NN + BLK - 1) / BLK;
    const int gW  = (NN * 64 + BLK - 1) / BLK;     // wave-per-node
    auto gNF = [&](int f) { return (NN * f + BLK - 1) / BLK; };

    // ---- CSR build + dinv ----
    hipMemsetAsync(cnt, 0, NN * sizeof(int), stream);
    k_hist <<<gE, BLK, 0, stream>>>(dst, cnt);
    k_dinv <<<gN, BLK, 0, stream>>>(cnt, dinv);
    k_scan1<<<NBLK, SCAN_B, 0, stream>>>(cnt, rowp, bsum);
    k_scan2<<<1, 512, 0, stream>>>(bsum);
    k_scan3<<<gN, BLK, 0, stream>>>(rowp, bsum, cursor);
    k_fill <<<gE, BLK, 0, stream>>>(src, dst, cursor, csr);

    // ---- Layer 1: gather at F_in=5 (pad 8), then 5->64 GEMM + BN + ReLU ----
    k_stage1<<<gNF(8), BLK, 0, stream>>>(x, dinv, HS);
    k_gather<8, 0><<<gW, BLK, 0, stream>>>(rowp, cnt, csr, HS, dinv,
                                           nullptr, nullptr, nullptr, nullptr, nullptr, G);
    k_lin1<<<gNF(64), BLK, 0, stream>>>(G, W1, b1, g1, be1, m1, v1, X);

    // ---- Layer 2: 64 -> 32 GEMM, gather at 32, BN + ReLU ----
    k_linear_scale<64, 32, 32><<<gNF(32), BLK, 0, stream>>>(X, W2, dinv, HS);
    k_gather<32, 2><<<gW, BLK, 0, stream>>>(rowp, cnt, csr, HS, dinv, b2, g2, be2, m2, v2, X);

    // ---- Layer 3: 32 -> 16 GEMM, gather at 16, ReLU ----
    k_linear_scale<32, 16, 16><<<gNF(16), BLK, 0, stream>>>(X, W3, dinv, HS);
    k_gather<16, 1><<<gW, BLK, 0, stream>>>(rowp, cnt, csr, HS, dinv, b3,
                                            nullptr, nullptr, nullptr, nullptr, X);

    // ---- Layer 4: 16 -> 3 GEMM (pad 4), gather at 4, logits ----
    k_linear_scale<16, 3, 4><<<gNF(4), BLK, 0, stream>>>(X, W4, dinv, HS);
    k_gather<4, 3><<<gW, BLK, 0, stream>>>(rowp, cnt, csr, HS, dinv, b4,
                                           nullptr, nullptr, nullptr, nullptr, out);
}